// Round 5
// baseline (84.255 us; speedup 1.0000x reference)
//
#include <hip/hip_runtime.h>

#define DIM 256
#define NSEG 2048
#define NATOMS 262144
#define TA 8                          /* atoms per wave-tile */
#define NTILES (NATOMS / TA)          /* 32768, exact */
#define SLOTS (NSEG + NTILES)         /* 34816 */
#define TPW 4                         /* tiles per wave (pipelined) */
#define WPB 4                         /* waves per block */
#define NBLK (NTILES / (WPB * TPW))   /* 2048 blocks */

// index_list may arrive as int64 (reference dtype) or int32. Detect on-device:
// for int64, word[1] is the high half of offset 0 (== 0); for int32, word[1]
// is the first interior offset (>= 1).
__device__ __forceinline__ long long load_off(const void* p, int i, int is64) {
  if (is64) return ((const long long*)p)[i];
  return (long long)((const int*)p)[i];
}

// Wave-wide sum with result broadcast to ALL lanes.
// DPP (VALU) for strides 1,2,4,8; ds_swizzle for 16; shfl for 32.
// quad_perm[1,0,3,2]=0xB1 (xor1), quad_perm[2,3,0,1]=0x4E (xor2),
// row_half_mirror=0x141 (cross-quad in 8), row_mirror=0x140 (cross-8 in 16).
__device__ __forceinline__ float wave_sum_b(float v) {
  int x;
  x = __builtin_amdgcn_update_dpp(0, __float_as_int(v), 0xB1, 0xF, 0xF, true);
  v += __int_as_float(x);
  x = __builtin_amdgcn_update_dpp(0, __float_as_int(v), 0x4E, 0xF, 0xF, true);
  v += __int_as_float(x);
  x = __builtin_amdgcn_update_dpp(0, __float_as_int(v), 0x141, 0xF, 0xF, true);
  v += __int_as_float(x);
  x = __builtin_amdgcn_update_dpp(0, __float_as_int(v), 0x140, 0xF, 0xF, true);
  v += __int_as_float(x);
  v += __int_as_float(__builtin_amdgcn_ds_swizzle(__float_as_int(v), 0x401F));
  v += __shfl_xor(v, 32);
  return v;
}

// s0tab[u] = segment of tile u's FIRST atom; s1tab[u] = segment of its LAST
// atom. One thread per segment scatter-writes its covered tile ranges.
__global__ void seg_of_tile(const void* __restrict__ offs_raw,
                            int* __restrict__ s0tab,
                            int* __restrict__ s1tab)
{
  int s = blockIdx.x * blockDim.x + threadIdx.x;
  if (s >= NSEG) return;
  const int is64 = (((const int*)offs_raw)[1] == 0);
  const int lo = (int)load_off(offs_raw, s, is64);
  const int hi = (int)load_off(offs_raw, s + 1, is64);
  // first atom u*TA in [lo,hi)
  {
    int u0 = (lo + TA - 1) / TA;
    int u1 = (hi + TA - 1) / TA - 1;
    for (int u = u0; u <= u1; ++u) s0tab[u] = s;
  }
  // last atom u*TA+TA-1 in [lo,hi)
  {
    int u0 = lo / TA;
    int u1 = hi >= TA ? (hi - TA) / TA : -1;
    for (int u = u0; u <= u1; ++u) s1tab[u] = s;
  }
}

#define LOADT(R, sA, sB, uu) do {                                         \
    const float4* fg_ = (const float4*)feat + (size_t)(uu) * (TA * 64);   \
    _Pragma("unroll")                                                     \
    for (int k_ = 0; k_ < TA; ++k_) R[k_] = fg_[k_ * 64 + lane];          \
    sA = s0tab[(uu)];                                                     \
    sB = s1tab[(uu)];                                                     \
  } while (0)

#define PROCT(R, sA, sB, uu) do {                                         \
    const int base_ = (uu) * TA;                                          \
    float lg_[TA];                                                        \
    _Pragma("unroll")                                                     \
    for (int k_ = 0; k_ < TA; ++k_) {                                     \
      float p_ = R[k_].x * wa4.x + R[k_].y * wa4.y +                      \
                 R[k_].z * wa4.z + R[k_].w * wa4.w;                       \
      lg_[k_] = wave_sum_b(p_);                                           \
    }                                                                     \
    if (sA == sB) {                                                       \
      float m_ = lg_[0];                                                  \
      _Pragma("unroll")                                                   \
      for (int k_ = 1; k_ < TA; ++k_) m_ = fmaxf(m_, lg_[k_]);            \
      float d_ = 0.f;                                                     \
      float4 acc_ = make_float4(0.f, 0.f, 0.f, 0.f);                      \
      _Pragma("unroll")                                                   \
      for (int k_ = 0; k_ < TA; ++k_) {                                   \
        float e_ = __expf(lg_[k_] - m_);                                  \
        d_ += e_;                                                         \
        acc_.x = fmaf(e_, R[k_].x, acc_.x);                               \
        acc_.y = fmaf(e_, R[k_].y, acc_.y);                               \
        acc_.z = fmaf(e_, R[k_].z, acc_.z);                               \
        acc_.w = fmaf(e_, R[k_].w, acc_.w);                               \
      }                                                                   \
      const int slot_ = sA + (uu);                                        \
      ((float4*)(accbuf + (size_t)slot_ * DIM))[lane] = acc_;             \
      if (lane == 0) { md[2 * slot_] = m_; md[2 * slot_ + 1] = d_; }      \
    } else {                                                              \
      for (int s_ = sA; s_ <= sB; ++s_) {                                 \
        int lo_ = (int)load_off(offs_raw, s_, is64);                      \
        int hi_ = (int)load_off(offs_raw, s_ + 1, is64);                  \
        int la_ = lo_ - base_; la_ = la_ > 0 ? la_ : 0;                   \
        int lb_ = hi_ - base_; lb_ = lb_ < TA ? lb_ : TA;                 \
        float m_ = -INFINITY;                                             \
        _Pragma("unroll")                                                 \
        for (int k_ = 0; k_ < TA; ++k_)                                   \
          if (k_ >= la_ && k_ < lb_) m_ = fmaxf(m_, lg_[k_]);             \
        float d_ = 0.f;                                                   \
        float4 acc_ = make_float4(0.f, 0.f, 0.f, 0.f);                    \
        _Pragma("unroll")                                                 \
        for (int k_ = 0; k_ < TA; ++k_) {                                 \
          bool v_ = (k_ >= la_ && k_ < lb_);                              \
          float e_ = v_ ? __expf(lg_[k_] - m_) : 0.f;                     \
          d_ += e_;                                                       \
          acc_.x = fmaf(e_, R[k_].x, acc_.x);                             \
          acc_.y = fmaf(e_, R[k_].y, acc_.y);                             \
          acc_.z = fmaf(e_, R[k_].z, acc_.z);                             \
          acc_.w = fmaf(e_, R[k_].w, acc_.w);                             \
        }                                                                 \
        const int slot_ = s_ + (uu);                                      \
        ((float4*)(accbuf + (size_t)slot_ * DIM))[lane] = acc_;           \
        if (lane == 0) { md[2 * slot_] = m_; md[2 * slot_ + 1] = d_; }    \
      }                                                                   \
    }                                                                     \
  } while (0)

// Wave-autonomous, depth-2 software-pipelined pooling: tile t+1's 8 loads are
// in flight while tile t's logits/softmax/weighted-sum compute runs.
__global__ __launch_bounds__(256, 4)
void pool_waves(const float* __restrict__ feat,
                const void* __restrict__ offs_raw,
                const float* __restrict__ Wa,
                const int* __restrict__ s0tab,
                const int* __restrict__ s1tab,
                float* __restrict__ md,
                float* __restrict__ accbuf)
{
  const int lane = threadIdx.x & 63;
  const int wv   = threadIdx.x >> 6;
  const int wid  = blockIdx.x * WPB + wv;
  const int u0   = wid * TPW;
  const int is64 = (((const int*)offs_raw)[1] == 0);

  const float4 wa4 = ((const float4*)Wa)[lane];

  float4 A[TA], B[TA];
  int sA0, sB0, sA1, sB1;

  LOADT(A, sA0, sB0, u0 + 0);
  LOADT(B, sA1, sB1, u0 + 1);
  PROCT(A, sA0, sB0, u0 + 0);
  LOADT(A, sA0, sB0, u0 + 2);
  PROCT(B, sA1, sB1, u0 + 1);
  LOADT(B, sA1, sB1, u0 + 3);
  PROCT(A, sA0, sB0, u0 + 2);
  PROCT(B, sA1, sB1, u0 + 3);
}

// wave-per-segment flash-merge, chunk-of-64: each LANE owns one partial slot
// (parallel max/denominator via butterflies), then a 4-unrolled accumulate
// over the chunk's slots with scales broadcast from LDS.
__global__ __launch_bounds__(256, 2)
void merge_project(const float* __restrict__ md,
                   const float* __restrict__ accbuf,
                   const void* __restrict__ offs_raw,
                   const float* __restrict__ Wo,
                   const float* __restrict__ bo,
                   float* __restrict__ out)
{
  __shared__ float pooled[4][DIM];
  __shared__ float sc_s[4][64];
  const int tid  = threadIdx.x;
  const int lane = tid & 63;
  const int wv   = tid >> 6;
  const int is64 = (((const int*)offs_raw)[1] == 0);
  const int s    = blockIdx.x * 4 + wv;

  {
    const int lo = (int)load_off(offs_raw, s, is64);
    const int hi = (int)load_off(offs_raw, s + 1, is64);
    const int u0 = lo / TA;
    const int u1 = (hi - 1) / TA;
    const int n  = u1 - u0 + 1;

    float M = -INFINITY, D = 0.f;
    float4 acc = make_float4(0.f, 0.f, 0.f, 0.f);

    for (int c0 = 0; c0 < n; c0 += 64) {
      const int j = c0 + lane;
      const bool v = (j < n);
      const int slot = s + u0 + j;
      float mj = v ? md[2 * slot] : -INFINITY;
      float dj = v ? md[2 * slot + 1] : 0.f;

      float Mc = mj;                     // chunk max -> all lanes
      Mc = fmaxf(Mc, __shfl_xor(Mc, 32));
      Mc = fmaxf(Mc, __shfl_xor(Mc, 16));
      Mc = fmaxf(Mc, __shfl_xor(Mc, 8));
      Mc = fmaxf(Mc, __shfl_xor(Mc, 4));
      Mc = fmaxf(Mc, __shfl_xor(Mc, 2));
      Mc = fmaxf(Mc, __shfl_xor(Mc, 1));
      const float Mn = fmaxf(M, Mc);
      const float rs = (c0 == 0) ? 0.f : __expf(M - Mn);  // avoid -inf - -inf
      const float scj = __expf(mj - Mn);                  // 0 for invalid lanes

      float t = dj * scj;                // chunk denom -> all lanes
      t += __shfl_xor(t, 32);
      t += __shfl_xor(t, 16);
      t += __shfl_xor(t, 8);
      t += __shfl_xor(t, 4);
      t += __shfl_xor(t, 2);
      t += __shfl_xor(t, 1);
      D = D * rs + t;

      sc_s[wv][lane] = scj;              // wave-coherent LDS stage

      acc.x *= rs; acc.y *= rs; acc.z *= rs; acc.w *= rs;

      const int cn = (n - c0) < 64 ? (n - c0) : 64;
      const float4* ab = (const float4*)(accbuf + (size_t)(s + u0 + c0) * DIM);
      int jj = 0;
      for (; jj + 4 <= cn; jj += 4) {    // 4 independent 1-KiB reads in flight
        float4 a0 = ab[(size_t)(jj + 0) * 64 + lane];
        float4 a1 = ab[(size_t)(jj + 1) * 64 + lane];
        float4 a2 = ab[(size_t)(jj + 2) * 64 + lane];
        float4 a3 = ab[(size_t)(jj + 3) * 64 + lane];
        float s0 = sc_s[wv][jj + 0], s1 = sc_s[wv][jj + 1];
        float s2 = sc_s[wv][jj + 2], s3 = sc_s[wv][jj + 3];
        acc.x = fmaf(s0, a0.x, fmaf(s1, a1.x, fmaf(s2, a2.x, fmaf(s3, a3.x, acc.x))));
        acc.y = fmaf(s0, a0.y, fmaf(s1, a1.y, fmaf(s2, a2.y, fmaf(s3, a3.y, acc.y))));
        acc.z = fmaf(s0, a0.z, fmaf(s1, a1.z, fmaf(s2, a2.z, fmaf(s3, a3.z, acc.z))));
        acc.w = fmaf(s0, a0.w, fmaf(s1, a1.w, fmaf(s2, a2.w, fmaf(s3, a3.w, acc.w))));
      }
      for (; jj < cn; ++jj) {
        float4 a0 = ab[(size_t)jj * 64 + lane];
        float s0 = sc_s[wv][jj];
        acc.x = fmaf(s0, a0.x, acc.x);
        acc.y = fmaf(s0, a0.y, acc.y);
        acc.z = fmaf(s0, a0.z, acc.z);
        acc.w = fmaf(s0, a0.w, acc.w);
      }
      M = Mn;
    }

    const float inv = 1.f / D;
    ((float4*)pooled[wv])[lane] =
        make_float4(acc.x * inv, acc.y * inv, acc.z * inv, acc.w * inv);
  }
  __syncthreads();

  // out[4 x 256] = pooled @ Wo + bo ; thread owns output dim tid
  float o0 = 0.f, o1 = 0.f, o2 = 0.f, o3 = 0.f;
  for (int k = 0; k < DIM; ++k) {
    float w = Wo[k * DIM + tid];           // coalesced; Wo is L2-resident
    o0 = fmaf(pooled[0][k], w, o0);        // LDS broadcast reads
    o1 = fmaf(pooled[1][k], w, o1);
    o2 = fmaf(pooled[2][k], w, o2);
    o3 = fmaf(pooled[3][k], w, o3);
  }
  const float b = bo[tid];
  const int sb = blockIdx.x * 4;
  out[(size_t)(sb + 0) * DIM + tid] = o0 + b;
  out[(size_t)(sb + 1) * DIM + tid] = o1 + b;
  out[(size_t)(sb + 2) * DIM + tid] = o2 + b;
  out[(size_t)(sb + 3) * DIM + tid] = o3 + b;
}

extern "C" void kernel_launch(void* const* d_in, const int* in_sizes, int n_in,
                              void* d_out, int out_size, void* d_ws, size_t ws_size,
                              hipStream_t stream)
{
  const float* feat = (const float*)d_in[0];
  const void*  offs = d_in[1];
  const float* Wa   = (const float*)d_in[2];
  /* d_in[3] = ba: cancels under softmax shift invariance */
  const float* Wo   = (const float*)d_in[4];
  const float* bo   = (const float*)d_in[5];
  float* out = (float*)d_out;

  float* md     = (float*)d_ws;                    // [SLOTS][2]
  float* accbuf = md + 2 * SLOTS;                  // [SLOTS][DIM]
  int*   s0tab  = (int*)(accbuf + (size_t)SLOTS * DIM);  // [NTILES]
  int*   s1tab  = s0tab + NTILES;                  // [NTILES]

  hipLaunchKernelGGL(seg_of_tile, dim3((NSEG + 255) / 256), dim3(256), 0, stream,
                     offs, s0tab, s1tab);
  hipLaunchKernelGGL(pool_waves, dim3(NBLK), dim3(256), 0, stream,
                     feat, offs, Wa, s0tab, s1tab, md, accbuf);
  hipLaunchKernelGGL(merge_project, dim3(NSEG / 4), dim3(256), 0, stream,
                     md, accbuf, offs, Wo, bo, out);
}

// Round 6
// 81.980 us; speedup vs baseline: 1.0278x; 1.0278x over previous
//
#include <hip/hip_runtime.h>

#define DIM 256
#define NSEG 2048
#define NATOMS 262144
#define TA 8                          /* atoms per wave-tile */
#define NTILES (NATOMS / TA)          /* 32768, exact */
#define SLOTS (NSEG + NTILES)         /* 34816 */
#define WPB 4                         /* waves per block */

// index_list may arrive as int64 (reference dtype) or int32. Detect on-device:
// for int64, word[1] is the high half of offset 0 (== 0); for int32, word[1]
// is the first interior offset (>= 1).
__device__ __forceinline__ long long load_off(const void* p, int i, int is64) {
  if (is64) return ((const long long*)p)[i];
  return (long long)((const int*)p)[i];
}

// Wave-wide sum, result broadcast to ALL lanes. DPP (VALU pipe) for strides
// 1,2,4,8; ds_swizzle for 16; shfl for 32.  Validated in R5 (absmax ok).
// quad_perm[1,0,3,2]=0xB1 (xor1), quad_perm[2,3,0,1]=0x4E (xor2),
// row_half_mirror=0x141, row_mirror=0x140.
__device__ __forceinline__ float wave_sum_b(float v) {
  int x;
  x = __builtin_amdgcn_update_dpp(0, __float_as_int(v), 0xB1, 0xF, 0xF, true);
  v += __int_as_float(x);
  x = __builtin_amdgcn_update_dpp(0, __float_as_int(v), 0x4E, 0xF, 0xF, true);
  v += __int_as_float(x);
  x = __builtin_amdgcn_update_dpp(0, __float_as_int(v), 0x141, 0xF, 0xF, true);
  v += __int_as_float(x);
  x = __builtin_amdgcn_update_dpp(0, __float_as_int(v), 0x140, 0xF, 0xF, true);
  v += __int_as_float(x);
  v += __int_as_float(__builtin_amdgcn_ds_swizzle(__float_as_int(v), 0x401F));
  v += __shfl_xor(v, 32);
  return v;
}

// s0tab[u] = segment of tile u's FIRST atom; s1tab[u] = segment of its LAST
// atom. One thread per segment scatter-writes its covered tile ranges.
// Removes ALL dependent off[] loads from pool's fast path.
__global__ void seg_of_tile(const void* __restrict__ offs_raw,
                            int* __restrict__ s0tab,
                            int* __restrict__ s1tab)
{
  int s = blockIdx.x * blockDim.x + threadIdx.x;
  if (s >= NSEG) return;
  const int is64 = (((const int*)offs_raw)[1] == 0);
  const int lo = (int)load_off(offs_raw, s, is64);
  const int hi = (int)load_off(offs_raw, s + 1, is64);
  {
    int u0 = (lo + TA - 1) / TA;
    int u1 = (hi + TA - 1) / TA - 1;
    for (int u = u0; u <= u1; ++u) s0tab[u] = s;
  }
  {
    int u0 = lo / TA;
    int u1 = hi >= TA ? (hi - TA) / TA : -1;
    for (int u = u0; u <= u1; ++u) s1tab[u] = s;
  }
}

// Wave-autonomous pooling: zero LDS, zero barriers, no spills.
// R6: 6 blocks/CU (24 waves/CU) for more loads in flight; est ~70 VGPR
// fits the ~85-VGPR budget at 6 waves/SIMD.
__global__ __launch_bounds__(256, 6)
void pool_waves(const float* __restrict__ feat,
                const void* __restrict__ offs_raw,
                const float* __restrict__ Wa,
                const int* __restrict__ s0tab,
                const int* __restrict__ s1tab,
                float* __restrict__ md,
                float* __restrict__ accbuf)
{
  const int lane = threadIdx.x & 63;
  const int wv   = threadIdx.x >> 6;
  const int u    = blockIdx.x * WPB + wv;
  const int base = u * TA;
  const int is64 = (((const int*)offs_raw)[1] == 0);

  // tile-range table first (L2-hot, needed late; no dependents on feat path)
  const int s0 = s0tab[u];
  const int s1 = s1tab[u];

  const float4 wa4 = ((const float4*)Wa)[lane];
  const float4* fg = (const float4*)feat + (size_t)base * (DIM / 4);

  // 8 coalesced 1-KiB row loads, all independent and in flight at once
  float4 r[TA];
#pragma unroll
  for (int k = 0; k < TA; ++k) r[k] = fg[(size_t)k * 64 + lane];

  // per-atom logits, result broadcast to all 64 lanes
  float lg[TA];
#pragma unroll
  for (int k = 0; k < TA; ++k) {
    float p = r[k].x * wa4.x + r[k].y * wa4.y + r[k].z * wa4.z + r[k].w * wa4.w;
    lg[k] = wave_sum_b(p);
  }

  if (s0 == s1) {
    // fast path (~94%): whole tile inside one segment
    float m = lg[0];
#pragma unroll
    for (int k = 1; k < TA; ++k) m = fmaxf(m, lg[k]);
    float d = 0.f;
    float4 acc = make_float4(0.f, 0.f, 0.f, 0.f);
#pragma unroll
    for (int k = 0; k < TA; ++k) {
      float e = __expf(lg[k] - m);
      d += e;
      acc.x = fmaf(e, r[k].x, acc.x);
      acc.y = fmaf(e, r[k].y, acc.y);
      acc.z = fmaf(e, r[k].z, acc.z);
      acc.w = fmaf(e, r[k].w, acc.w);
    }
    const int slot = s0 + u;           // injective over intersecting (s,u)
    ((float4*)(accbuf + (size_t)slot * DIM))[lane] = acc;
    if (lane == 0) *((float2*)(md + 2 * slot)) = make_float2(m, d);
  } else {
    for (int s = s0; s <= s1; ++s) {   // wave-uniform loop (~6% of tiles)
      int lo = (int)load_off(offs_raw, s, is64);
      int hi = (int)load_off(offs_raw, s + 1, is64);
      int la = lo - base; la = la > 0 ? la : 0;
      int lb = hi - base; lb = lb < TA ? lb : TA;
      float m = -INFINITY;
#pragma unroll
      for (int k = 0; k < TA; ++k)
        if (k >= la && k < lb) m = fmaxf(m, lg[k]);
      float d = 0.f;
      float4 acc = make_float4(0.f, 0.f, 0.f, 0.f);
#pragma unroll
      for (int k = 0; k < TA; ++k) {
        bool v = (k >= la && k < lb);
        float e = v ? __expf(lg[k] - m) : 0.f;
        d += e;
        acc.x = fmaf(e, r[k].x, acc.x);
        acc.y = fmaf(e, r[k].y, acc.y);
        acc.z = fmaf(e, r[k].z, acc.z);
        acc.w = fmaf(e, r[k].w, acc.w);
      }
      const int slot = s + u;
      ((float4*)(accbuf + (size_t)slot * DIM))[lane] = acc;
      if (lane == 0) *((float2*)(md + 2 * slot)) = make_float2(m, d);
    }
  }
}

// wave-per-segment flash-merge, chunk-of-64: each LANE owns one partial slot
// (parallel max/denominator via butterflies), then a 4-unrolled accumulate
// over the chunk's slots with scales broadcast from LDS.
__global__ __launch_bounds__(256, 2)
void merge_project(const float* __restrict__ md,
                   const float* __restrict__ accbuf,
                   const void* __restrict__ offs_raw,
                   const float* __restrict__ Wo,
                   const float* __restrict__ bo,
                   float* __restrict__ out)
{
  __shared__ float pooled[4][DIM];
  __shared__ float sc_s[4][64];
  const int tid  = threadIdx.x;
  const int lane = tid & 63;
  const int wv   = tid >> 6;
  const int is64 = (((const int*)offs_raw)[1] == 0);
  const int s    = blockIdx.x * 4 + wv;

  {
    const int lo = (int)load_off(offs_raw, s, is64);
    const int hi = (int)load_off(offs_raw, s + 1, is64);
    const int u0 = lo / TA;
    const int u1 = (hi - 1) / TA;
    const int n  = u1 - u0 + 1;

    float M = -INFINITY, D = 0.f;
    float4 acc = make_float4(0.f, 0.f, 0.f, 0.f);

    for (int c0 = 0; c0 < n; c0 += 64) {
      const int j = c0 + lane;
      const bool v = (j < n);
      const int slot = s + u0 + j;
      float mj = v ? md[2 * slot] : -INFINITY;
      float dj = v ? md[2 * slot + 1] : 0.f;

      float Mc = mj;                     // chunk max -> all lanes
      Mc = fmaxf(Mc, __shfl_xor(Mc, 32));
      Mc = fmaxf(Mc, __shfl_xor(Mc, 16));
      Mc = fmaxf(Mc, __shfl_xor(Mc, 8));
      Mc = fmaxf(Mc, __shfl_xor(Mc, 4));
      Mc = fmaxf(Mc, __shfl_xor(Mc, 2));
      Mc = fmaxf(Mc, __shfl_xor(Mc, 1));
      const float Mn = fmaxf(M, Mc);
      const float rs = (c0 == 0) ? 0.f : __expf(M - Mn);  // avoid -inf - -inf
      const float scj = __expf(mj - Mn);                  // 0 for invalid lanes

      float t = dj * scj;                // chunk denom -> all lanes
      t += __shfl_xor(t, 32);
      t += __shfl_xor(t, 16);
      t += __shfl_xor(t, 8);
      t += __shfl_xor(t, 4);
      t += __shfl_xor(t, 2);
      t += __shfl_xor(t, 1);
      D = D * rs + t;

      sc_s[wv][lane] = scj;              // wave-coherent LDS stage

      acc.x *= rs; acc.y *= rs; acc.z *= rs; acc.w *= rs;

      const int cn = (n - c0) < 64 ? (n - c0) : 64;
      const float4* ab = (const float4*)(accbuf + (size_t)(s + u0 + c0) * DIM);
      int jj = 0;
      for (; jj + 4 <= cn; jj += 4) {    // 4 independent 1-KiB reads in flight
        float4 a0 = ab[(size_t)(jj + 0) * 64 + lane];
        float4 a1 = ab[(size_t)(jj + 1) * 64 + lane];
        float4 a2 = ab[(size_t)(jj + 2) * 64 + lane];
        float4 a3 = ab[(size_t)(jj + 3) * 64 + lane];
        float s0 = sc_s[wv][jj + 0], s1 = sc_s[wv][jj + 1];
        float s2 = sc_s[wv][jj + 2], s3 = sc_s[wv][jj + 3];
        acc.x = fmaf(s0, a0.x, fmaf(s1, a1.x, fmaf(s2, a2.x, fmaf(s3, a3.x, acc.x))));
        acc.y = fmaf(s0, a0.y, fmaf(s1, a1.y, fmaf(s2, a2.y, fmaf(s3, a3.y, acc.y))));
        acc.z = fmaf(s0, a0.z, fmaf(s1, a1.z, fmaf(s2, a2.z, fmaf(s3, a3.z, acc.z))));
        acc.w = fmaf(s0, a0.w, fmaf(s1, a1.w, fmaf(s2, a2.w, fmaf(s3, a3.w, acc.w))));
      }
      for (; jj < cn; ++jj) {
        float4 a0 = ab[(size_t)jj * 64 + lane];
        float s0 = sc_s[wv][jj];
        acc.x = fmaf(s0, a0.x, acc.x);
        acc.y = fmaf(s0, a0.y, acc.y);
        acc.z = fmaf(s0, a0.z, acc.z);
        acc.w = fmaf(s0, a0.w, acc.w);
      }
      M = Mn;
    }

    const float inv = 1.f / D;
    ((float4*)pooled[wv])[lane] =
        make_float4(acc.x * inv, acc.y * inv, acc.z * inv, acc.w * inv);
  }
  __syncthreads();

  // out[4 x 256] = pooled @ Wo + bo ; thread owns output dim tid
  float o0 = 0.f, o1 = 0.f, o2 = 0.f, o3 = 0.f;
  for (int k = 0; k < DIM; ++k) {
    float w = Wo[k * DIM + tid];           // coalesced; Wo is L2-resident
    o0 = fmaf(pooled[0][k], w, o0);        // LDS broadcast reads
    o1 = fmaf(pooled[1][k], w, o1);
    o2 = fmaf(pooled[2][k], w, o2);
    o3 = fmaf(pooled[3][k], w, o3);
  }
  const float b = bo[tid];
  const int sb = blockIdx.x * 4;
  out[(size_t)(sb + 0) * DIM + tid] = o0 + b;
  out[(size_t)(sb + 1) * DIM + tid] = o1 + b;
  out[(size_t)(sb + 2) * DIM + tid] = o2 + b;
  out[(size_t)(sb + 3) * DIM + tid] = o3 + b;
}

extern "C" void kernel_launch(void* const* d_in, const int* in_sizes, int n_in,
                              void* d_out, int out_size, void* d_ws, size_t ws_size,
                              hipStream_t stream)
{
  const float* feat = (const float*)d_in[0];
  const void*  offs = d_in[1];
  const float* Wa   = (const float*)d_in[2];
  /* d_in[3] = ba: cancels under softmax shift invariance */
  const float* Wo   = (const float*)d_in[4];
  const float* bo   = (const float*)d_in[5];
  float* out = (float*)d_out;

  float* md     = (float*)d_ws;                    // [SLOTS][2]
  float* accbuf = md + 2 * SLOTS;                  // [SLOTS][DIM]
  int*   s0tab  = (int*)(accbuf + (size_t)SLOTS * DIM);  // [NTILES]
  int*   s1tab  = s0tab + NTILES;                  // [NTILES]

  hipLaunchKernelGGL(seg_of_tile, dim3((NSEG + 255) / 256), dim3(256), 0, stream,
                     offs, s0tab, s1tab);
  hipLaunchKernelGGL(pool_waves, dim3(NTILES / WPB), dim3(256), 0, stream,
                     feat, offs, Wa, s0tab, s1tab, md, accbuf);
  hipLaunchKernelGGL(merge_project, dim3(NSEG / 4), dim3(256), 0, stream,
                     md, accbuf, offs, Wo, bo, out);
}

// Round 7
// 77.672 us; speedup vs baseline: 1.0848x; 1.0555x over previous
//
#include <hip/hip_runtime.h>

#define DIM 256
#define NSEG 2048
#define NATOMS 262144
#define TA 8                          /* atoms per wave-tile */
#define NTILES (NATOMS / TA)          /* 32768, exact */
#define SLOTS (NSEG + NTILES)         /* 34816 */
#define WPB 4                         /* waves per block */

// index_list may arrive as int64 (reference dtype) or int32. Detect on-device:
// for int64, word[1] is the high half of offset 0 (== 0); for int32, word[1]
// is the first interior offset (>= 1).
__device__ __forceinline__ long long load_off(const void* p, int i, int is64) {
  if (is64) return ((const long long*)p)[i];
  return (long long)((const int*)p)[i];
}

// Wave-wide sum, result broadcast to ALL lanes. DPP (VALU pipe) for strides
// 1,2,4,8; ds_swizzle for 16; shfl for 32.  Validated R5/R6 (absmax ok).
__device__ __forceinline__ float wave_sum_b(float v) {
  int x;
  x = __builtin_amdgcn_update_dpp(0, __float_as_int(v), 0xB1, 0xF, 0xF, true);
  v += __int_as_float(x);
  x = __builtin_amdgcn_update_dpp(0, __float_as_int(v), 0x4E, 0xF, 0xF, true);
  v += __int_as_float(x);
  x = __builtin_amdgcn_update_dpp(0, __float_as_int(v), 0x141, 0xF, 0xF, true);
  v += __int_as_float(x);
  x = __builtin_amdgcn_update_dpp(0, __float_as_int(v), 0x140, 0xF, 0xF, true);
  v += __int_as_float(x);
  v += __int_as_float(__builtin_amdgcn_ds_swizzle(__float_as_int(v), 0x401F));
  v += __shfl_xor(v, 32);
  return v;
}

// fp32 -> bf16 (RNE), packed pair; and unpack helpers.
__device__ __forceinline__ unsigned bf16rne(float f) {
  unsigned u = __float_as_uint(f);
  return (u + 0x7FFFu + ((u >> 16) & 1u)) >> 16;
}
__device__ __forceinline__ unsigned pack2(float a, float b) {
  return bf16rne(a) | (bf16rne(b) << 16);
}
__device__ __forceinline__ float4 unpack4(uint2 u) {
  float4 f;
  f.x = __uint_as_float(u.x << 16);
  f.y = __uint_as_float(u.x & 0xFFFF0000u);
  f.z = __uint_as_float(u.y << 16);
  f.w = __uint_as_float(u.y & 0xFFFF0000u);
  return f;
}

// s0tab[u] = segment of tile u's FIRST atom; s1tab[u] = segment of its LAST
// atom. One thread per segment scatter-writes its covered tile ranges.
__global__ void seg_of_tile(const void* __restrict__ offs_raw,
                            int* __restrict__ s0tab,
                            int* __restrict__ s1tab)
{
  int s = blockIdx.x * blockDim.x + threadIdx.x;
  if (s >= NSEG) return;
  const int is64 = (((const int*)offs_raw)[1] == 0);
  const int lo = (int)load_off(offs_raw, s, is64);
  const int hi = (int)load_off(offs_raw, s + 1, is64);
  {
    int u0 = (lo + TA - 1) / TA;
    int u1 = (hi + TA - 1) / TA - 1;
    for (int u = u0; u <= u1; ++u) s0tab[u] = s;
  }
  {
    int u0 = lo / TA;
    int u1 = hi >= TA ? (hi - TA) / TA : -1;
    for (int u = u0; u <= u1; ++u) s1tab[u] = s;
  }
}

// Wave-autonomous pooling: zero LDS, zero barriers, no spills (cap 128 VGPR
// at 4 blocks/CU -- the R4-proven config). Partials stored as bf16.
__global__ __launch_bounds__(256, 4)
void pool_waves(const float* __restrict__ feat,
                const void* __restrict__ offs_raw,
                const float* __restrict__ Wa,
                const int* __restrict__ s0tab,
                const int* __restrict__ s1tab,
                float* __restrict__ md,
                uint2* __restrict__ accbuf)
{
  const int lane = threadIdx.x & 63;
  const int wv   = threadIdx.x >> 6;
  const int u    = blockIdx.x * WPB + wv;
  const int base = u * TA;
  const int is64 = (((const int*)offs_raw)[1] == 0);

  const float4* fg = (const float4*)feat + (size_t)base * (DIM / 4);

  // 8 coalesced 1-KiB row loads first -- nothing ahead of them in the queue
  float4 r[TA];
#pragma unroll
  for (int k = 0; k < TA; ++k) r[k] = fg[(size_t)k * 64 + lane];

  // tile-range table + Wa after the big loads (L2-hot, needed later)
  const int s0 = s0tab[u];
  const int s1 = s1tab[u];
  const float4 wa4 = ((const float4*)Wa)[lane];

  // per-atom logits, result broadcast to all 64 lanes
  float lg[TA];
#pragma unroll
  for (int k = 0; k < TA; ++k) {
    float p = r[k].x * wa4.x + r[k].y * wa4.y + r[k].z * wa4.z + r[k].w * wa4.w;
    lg[k] = wave_sum_b(p);
  }

  if (s0 == s1) {
    // fast path (~94%): whole tile inside one segment
    float m = lg[0];
#pragma unroll
    for (int k = 1; k < TA; ++k) m = fmaxf(m, lg[k]);
    float d = 0.f;
    float4 acc = make_float4(0.f, 0.f, 0.f, 0.f);
#pragma unroll
    for (int k = 0; k < TA; ++k) {
      float e = __expf(lg[k] - m);
      d += e;
      acc.x = fmaf(e, r[k].x, acc.x);
      acc.y = fmaf(e, r[k].y, acc.y);
      acc.z = fmaf(e, r[k].z, acc.z);
      acc.w = fmaf(e, r[k].w, acc.w);
    }
    const int slot = s0 + u;           // injective over intersecting (s,u)
    accbuf[(size_t)slot * 64 + lane] = make_uint2(pack2(acc.x, acc.y),
                                                  pack2(acc.z, acc.w));
    if (lane == 0) *((float2*)(md + 2 * slot)) = make_float2(m, d);
  } else {
    for (int s = s0; s <= s1; ++s) {   // wave-uniform loop (~6% of tiles)
      int lo = (int)load_off(offs_raw, s, is64);
      int hi = (int)load_off(offs_raw, s + 1, is64);
      int la = lo - base; la = la > 0 ? la : 0;
      int lb = hi - base; lb = lb < TA ? lb : TA;
      float m = -INFINITY;
#pragma unroll
      for (int k = 0; k < TA; ++k)
        if (k >= la && k < lb) m = fmaxf(m, lg[k]);
      float d = 0.f;
      float4 acc = make_float4(0.f, 0.f, 0.f, 0.f);
#pragma unroll
      for (int k = 0; k < TA; ++k) {
        bool v = (k >= la && k < lb);
        float e = v ? __expf(lg[k] - m) : 0.f;
        d += e;
        acc.x = fmaf(e, r[k].x, acc.x);
        acc.y = fmaf(e, r[k].y, acc.y);
        acc.z = fmaf(e, r[k].z, acc.z);
        acc.w = fmaf(e, r[k].w, acc.w);
      }
      const int slot = s + u;
      accbuf[(size_t)slot * 64 + lane] = make_uint2(pack2(acc.x, acc.y),
                                                    pack2(acc.z, acc.w));
      if (lane == 0) *((float2*)(md + 2 * slot)) = make_float2(m, d);
    }
  }
}

// wave-per-segment flash-merge, chunk-of-64: each LANE owns one partial slot
// (parallel max/denominator via butterflies), then a 4-unrolled accumulate
// over the chunk's bf16 slots with scales broadcast from LDS.
__global__ __launch_bounds__(256, 4)
void merge_project(const float* __restrict__ md,
                   const uint2* __restrict__ accbuf,
                   const void* __restrict__ offs_raw,
                   const float* __restrict__ Wo,
                   const float* __restrict__ bo,
                   float* __restrict__ out)
{
  __shared__ float pooled[4][DIM];
  __shared__ float sc_s[4][64];
  const int tid  = threadIdx.x;
  const int lane = tid & 63;
  const int wv   = tid >> 6;
  const int is64 = (((const int*)offs_raw)[1] == 0);
  const int s    = blockIdx.x * 4 + wv;

  {
    const int lo = (int)load_off(offs_raw, s, is64);
    const int hi = (int)load_off(offs_raw, s + 1, is64);
    const int u0 = lo / TA;
    const int u1 = (hi - 1) / TA;
    const int n  = u1 - u0 + 1;

    float M = -INFINITY, D = 0.f;
    float4 acc = make_float4(0.f, 0.f, 0.f, 0.f);

    for (int c0 = 0; c0 < n; c0 += 64) {
      const int j = c0 + lane;
      const bool v = (j < n);
      const int slot = s + u0 + j;
      float mj = v ? md[2 * slot] : -INFINITY;
      float dj = v ? md[2 * slot + 1] : 0.f;

      float Mc = mj;                     // chunk max -> all lanes
      Mc = fmaxf(Mc, __shfl_xor(Mc, 32));
      Mc = fmaxf(Mc, __shfl_xor(Mc, 16));
      Mc = fmaxf(Mc, __shfl_xor(Mc, 8));
      Mc = fmaxf(Mc, __shfl_xor(Mc, 4));
      Mc = fmaxf(Mc, __shfl_xor(Mc, 2));
      Mc = fmaxf(Mc, __shfl_xor(Mc, 1));
      const float Mn = fmaxf(M, Mc);
      const float rs = (c0 == 0) ? 0.f : __expf(M - Mn);  // avoid -inf - -inf
      const float scj = __expf(mj - Mn);                  // 0 for invalid lanes

      float t = dj * scj;                // chunk denom -> all lanes
      t += __shfl_xor(t, 32);
      t += __shfl_xor(t, 16);
      t += __shfl_xor(t, 8);
      t += __shfl_xor(t, 4);
      t += __shfl_xor(t, 2);
      t += __shfl_xor(t, 1);
      D = D * rs + t;

      sc_s[wv][lane] = scj;              // wave-coherent LDS stage

      acc.x *= rs; acc.y *= rs; acc.z *= rs; acc.w *= rs;

      const int cn = (n - c0) < 64 ? (n - c0) : 64;
      const uint2* ab = accbuf + (size_t)(s + u0 + c0) * 64;
      int jj = 0;
      for (; jj + 4 <= cn; jj += 4) {    // 4 independent 512-B reads in flight
        float4 a0 = unpack4(ab[(size_t)(jj + 0) * 64 + lane]);
        float4 a1 = unpack4(ab[(size_t)(jj + 1) * 64 + lane]);
        float4 a2 = unpack4(ab[(size_t)(jj + 2) * 64 + lane]);
        float4 a3 = unpack4(ab[(size_t)(jj + 3) * 64 + lane]);
        float s0 = sc_s[wv][jj + 0], s1 = sc_s[wv][jj + 1];
        float s2 = sc_s[wv][jj + 2], s3 = sc_s[wv][jj + 3];
        acc.x = fmaf(s0, a0.x, fmaf(s1, a1.x, fmaf(s2, a2.x, fmaf(s3, a3.x, acc.x))));
        acc.y = fmaf(s0, a0.y, fmaf(s1, a1.y, fmaf(s2, a2.y, fmaf(s3, a3.y, acc.y))));
        acc.z = fmaf(s0, a0.z, fmaf(s1, a1.z, fmaf(s2, a2.z, fmaf(s3, a3.z, acc.z))));
        acc.w = fmaf(s0, a0.w, fmaf(s1, a1.w, fmaf(s2, a2.w, fmaf(s3, a3.w, acc.w))));
      }
      for (; jj < cn; ++jj) {
        float4 a0 = unpack4(ab[(size_t)jj * 64 + lane]);
        float s0 = sc_s[wv][jj];
        acc.x = fmaf(s0, a0.x, acc.x);
        acc.y = fmaf(s0, a0.y, acc.y);
        acc.z = fmaf(s0, a0.z, acc.z);
        acc.w = fmaf(s0, a0.w, acc.w);
      }
      M = Mn;
    }

    const float inv = 1.f / D;
    ((float4*)pooled[wv])[lane] =
        make_float4(acc.x * inv, acc.y * inv, acc.z * inv, acc.w * inv);
  }
  __syncthreads();

  // out[4 x 256] = pooled @ Wo + bo ; thread owns output dim tid
  float o0 = 0.f, o1 = 0.f, o2 = 0.f, o3 = 0.f;
  for (int k = 0; k < DIM; ++k) {
    float w = Wo[k * DIM + tid];           // coalesced; Wo is L2-resident
    o0 = fmaf(pooled[0][k], w, o0);        // LDS broadcast reads
    o1 = fmaf(pooled[1][k], w, o1);
    o2 = fmaf(pooled[2][k], w, o2);
    o3 = fmaf(pooled[3][k], w, o3);
  }
  const float b = bo[tid];
  const int sb = blockIdx.x * 4;
  out[(size_t)(sb + 0) * DIM + tid] = o0 + b;
  out[(size_t)(sb + 1) * DIM + tid] = o1 + b;
  out[(size_t)(sb + 2) * DIM + tid] = o2 + b;
  out[(size_t)(sb + 3) * DIM + tid] = o3 + b;
}

extern "C" void kernel_launch(void* const* d_in, const int* in_sizes, int n_in,
                              void* d_out, int out_size, void* d_ws, size_t ws_size,
                              hipStream_t stream)
{
  const float* feat = (const float*)d_in[0];
  const void*  offs = d_in[1];
  const float* Wa   = (const float*)d_in[2];
  /* d_in[3] = ba: cancels under softmax shift invariance */
  const float* Wo   = (const float*)d_in[4];
  const float* bo   = (const float*)d_in[5];
  float* out = (float*)d_out;

  float* md     = (float*)d_ws;                    // [SLOTS][2] fp32
  uint2* accbuf = (uint2*)(md + 2 * SLOTS);        // [SLOTS][64] bf16x4
  int*   s0tab  = (int*)(accbuf + (size_t)SLOTS * 64);   // [NTILES]
  int*   s1tab  = s0tab + NTILES;                  // [NTILES]

  hipLaunchKernelGGL(seg_of_tile, dim3((NSEG + 255) / 256), dim3(256), 0, stream,
                     offs, s0tab, s1tab);
  hipLaunchKernelGGL(pool_waves, dim3(NTILES / WPB), dim3(256), 0, stream,
                     feat, offs, Wa, s0tab, s1tab, md, accbuf);
  hipLaunchKernelGGL(merge_project, dim3(NSEG / 4), dim3(256), 0, stream,
                     md, accbuf, offs, Wo, bo, out);
}